// Round 1
// baseline (1480.890 us; speedup 1.0000x reference)
//
#include <hip/hip_runtime.h>

#define N_NODES 300000
#define N_EDGES 600000
#define IN_DIMC 64
#define HIDC    128
#define NLAYERS 2
#define BN_EPS  1e-5f
#define INV_SQRT_H 0.08838834764831845f  // 1/sqrt(128)

// ---------------------------------------------------------------------------
// proj: h[N,128] = X[N,64] @ W[64,128] + b
// Block 256 threads, tile = 64 nodes x 128 ch. LDS: X 16KB + W 32KB = 48KB.
// Thread (tx=t&31, ty=t>>5) computes nodes (ty + 8i), channels 4*tx..4*tx+3.
// ---------------------------------------------------------------------------
__global__ __launch_bounds__(256) void proj_kernel(
    const float* __restrict__ X, const float* __restrict__ W,
    const float* __restrict__ b, float* __restrict__ h)
{
    __shared__ float Xs[64 * 64];
    __shared__ float Ws[64 * 128];
    const int t = threadIdx.x;
    const int base = blockIdx.x * 64;

    for (int i = t; i < 64 * 128 / 4; i += 256)
        ((float4*)Ws)[i] = ((const float4*)W)[i];

    for (int i = t; i < 64 * 64 / 4; i += 256) {
        int row = i >> 4;
        int n = base + row;
        float4 v = make_float4(0.f, 0.f, 0.f, 0.f);
        if (n < N_NODES) v = ((const float4*)(X + (size_t)n * IN_DIMC))[i & 15];
        ((float4*)Xs)[i] = v;
    }
    __syncthreads();

    const int tx = t & 31;
    const int ty = t >> 5;
    float4 acc[8];
#pragma unroll
    for (int i = 0; i < 8; ++i) acc[i] = make_float4(0.f, 0.f, 0.f, 0.f);

    for (int k = 0; k < 64; ++k) {
        float4 w = ((const float4*)(Ws + k * 128))[tx];
#pragma unroll
        for (int i = 0; i < 8; ++i) {
            float a = Xs[(ty + 8 * i) * 64 + k];
            acc[i].x += a * w.x; acc[i].y += a * w.y;
            acc[i].z += a * w.z; acc[i].w += a * w.w;
        }
    }
    float4 bias = ((const float4*)b)[tx];
#pragma unroll
    for (int i = 0; i < 8; ++i) {
        int n = base + ty + 8 * i;
        if (n < N_NODES) {
            float4 o;
            o.x = acc[i].x + bias.x; o.y = acc[i].y + bias.y;
            o.z = acc[i].z + bias.z; o.w = acc[i].w + bias.w;
            ((float4*)(h + (size_t)n * HIDC))[tx] = o;
        }
    }
}

// ---------------------------------------------------------------------------
// edge_agg: one wave (64 lanes) per edge; lane handles channels {lane, lane+64}.
//   key = dot(h[src], att_k)/sqrt(H); w = exp(key)/(1+len)
//   agg[dst] += w * h[src]   (fp32 global atomics)
// ---------------------------------------------------------------------------
__global__ __launch_bounds__(256) void edge_agg_kernel(
    const float* __restrict__ h, const int* __restrict__ src,
    const int* __restrict__ dst, const float* __restrict__ elen,
    const float* __restrict__ att_k, float* __restrict__ agg)
{
    const int lane = threadIdx.x & 63;
    const int e = blockIdx.x * 4 + (threadIdx.x >> 6);
    if (e >= N_EDGES) return;
    const int s = src[e];
    const int d = dst[e];
    const float* hs = h + (size_t)s * HIDC;
    float x0 = hs[lane];
    float x1 = hs[lane + 64];
    float p = x0 * att_k[lane] + x1 * att_k[lane + 64];
#pragma unroll
    for (int off = 32; off > 0; off >>= 1)
        p += __shfl_xor(p, off);
    float w = __expf(p * INV_SQRT_H) * (1.0f / (1.0f + elen[e]));
    float* ad = agg + (size_t)d * HIDC;
    atomicAdd(ad + lane, w * x0);
    atomicAdd(ad + lane + 64, w * x1);
}

// ---------------------------------------------------------------------------
// layer_gemm: h[n][cbase..cbase+63] += relu(agg[n]) @ W[:, cbase..cbase+63] + b
// Also accumulates per-channel sum / sumsq of the NEW h into stats[256] for BN.
// Block 256 threads, tile 64 nodes x 64 channels, K=128 staged in halves.
// LDS: As 64x68 (17.4KB, padded: rows land on distinct banks) + Ws 128x64
// (32KB) + red[128] -> ~50KB, 3 blocks/CU.
// Thread (tx=t&15, ty=t>>4): nodes ty+16i (i<4), channels cbase+4*tx..+3.
// ---------------------------------------------------------------------------
__global__ __launch_bounds__(256) void layer_gemm_kernel(
    float* __restrict__ h, const float* __restrict__ agg,
    const float* __restrict__ W, const float* __restrict__ b,
    float* __restrict__ stats)
{
    __shared__ float As[64 * 68];
    __shared__ float Ws[128 * 64];
    __shared__ float red[128];

    const int t = threadIdx.x;
    const int nbase = blockIdx.x * 64;
    const int cbase = blockIdx.y * 64;

    if (t < 128) red[t] = 0.f;

    // stage W column block [128 x 64]
    for (int i = t; i < 128 * 64 / 4; i += 256) {
        int k = i >> 4;
        int cg = i & 15;
        *(float4*)(Ws + k * 64 + cg * 4) =
            *(const float4*)(W + (size_t)k * HIDC + cbase + cg * 4);
    }

    const int tx = t & 15;
    const int ty = t >> 4;
    float4 acc[4];
#pragma unroll
    for (int i = 0; i < 4; ++i) acc[i] = make_float4(0.f, 0.f, 0.f, 0.f);

    for (int kb = 0; kb < HIDC; kb += 64) {
        // stage relu(agg) K-half [64 nodes x 64 k]
        for (int i = t; i < 64 * 64 / 4; i += 256) {
            int row = i >> 4;
            int cg = i & 15;
            int n = nbase + row;
            float4 v = make_float4(0.f, 0.f, 0.f, 0.f);
            if (n < N_NODES) {
                v = *(const float4*)(agg + (size_t)n * HIDC + kb + cg * 4);
                v.x = fmaxf(v.x, 0.f); v.y = fmaxf(v.y, 0.f);
                v.z = fmaxf(v.z, 0.f); v.w = fmaxf(v.w, 0.f);
            }
            *(float4*)(As + row * 68 + cg * 4) = v;
        }
        __syncthreads();
        for (int k2 = 0; k2 < 64; ++k2) {
            float4 w = *(const float4*)(Ws + (kb + k2) * 64 + tx * 4);
#pragma unroll
            for (int i = 0; i < 4; ++i) {
                float a = As[(ty + 16 * i) * 68 + k2];
                acc[i].x += a * w.x; acc[i].y += a * w.y;
                acc[i].z += a * w.z; acc[i].w += a * w.w;
            }
        }
        __syncthreads();
    }

    float4 bias = *(const float4*)(b + cbase + tx * 4);
    float sl[4] = {0.f, 0.f, 0.f, 0.f};
    float sq[4] = {0.f, 0.f, 0.f, 0.f};
#pragma unroll
    for (int i = 0; i < 4; ++i) {
        int n = nbase + ty + 16 * i;
        if (n < N_NODES) {
            float4* hp = (float4*)(h + (size_t)n * HIDC + cbase) + tx;
            float4 hv = *hp;
            float4 o;
            o.x = hv.x + acc[i].x + bias.x;
            o.y = hv.y + acc[i].y + bias.y;
            o.z = hv.z + acc[i].z + bias.z;
            o.w = hv.w + acc[i].w + bias.w;
            *hp = o;
            sl[0] += o.x; sq[0] += o.x * o.x;
            sl[1] += o.y; sq[1] += o.y * o.y;
            sl[2] += o.z; sq[2] += o.z * o.z;
            sl[3] += o.w; sq[3] += o.w * o.w;
        }
    }
#pragma unroll
    for (int j = 0; j < 4; ++j) {
        atomicAdd(&red[tx * 4 + j], sl[j]);
        atomicAdd(&red[64 + tx * 4 + j], sq[j]);
    }
    __syncthreads();
    if (t < 64) {
        atomicAdd(stats + cbase + t, red[t]);
        atomicAdd(stats + HIDC + cbase + t, red[64 + t]);
    }
}

// ---------------------------------------------------------------------------
// bn_apply: h = (h - mean) * rsqrt(var + eps) * gamma + beta, per channel
// stats[0..127] = sum, stats[128..255] = sumsq (over N nodes)
// ---------------------------------------------------------------------------
__global__ __launch_bounds__(256) void bn_kernel(
    float* __restrict__ h, const float* __restrict__ stats,
    const float* __restrict__ gamma, const float* __restrict__ beta)
{
    const float invN = 1.0f / (float)N_NODES;
    size_t idx = (size_t)blockIdx.x * 256 + threadIdx.x;  // float4 index
    if (idx >= (size_t)N_NODES * (HIDC / 4)) return;
    int cg = (int)(idx & 31);
    float4 s1 = ((const float4*)stats)[cg];
    float4 s2 = ((const float4*)(stats + HIDC))[cg];
    float4 g = ((const float4*)gamma)[cg];
    float4 be = ((const float4*)beta)[cg];
    float4 mean, sc;
    mean.x = s1.x * invN; mean.y = s1.y * invN;
    mean.z = s1.z * invN; mean.w = s1.w * invN;
    sc.x = g.x * rsqrtf(s2.x * invN - mean.x * mean.x + BN_EPS);
    sc.y = g.y * rsqrtf(s2.y * invN - mean.y * mean.y + BN_EPS);
    sc.z = g.z * rsqrtf(s2.z * invN - mean.z * mean.z + BN_EPS);
    sc.w = g.w * rsqrtf(s2.w * invN - mean.w * mean.w + BN_EPS);
    float4 v = ((float4*)h)[idx];
    v.x = (v.x - mean.x) * sc.x + be.x;
    v.y = (v.y - mean.y) * sc.y + be.y;
    v.z = (v.z - mean.z) * sc.z + be.z;
    v.w = (v.w - mean.w) * sc.w + be.w;
    ((float4*)h)[idx] = v;
}

// ---------------------------------------------------------------------------
extern "C" void kernel_launch(void* const* d_in, const int* in_sizes, int n_in,
                              void* d_out, int out_size, void* d_ws, size_t ws_size,
                              hipStream_t stream) {
    (void)in_sizes; (void)n_in; (void)out_size; (void)ws_size;
    const float* node_init = (const float*)d_in[0];
    const int*   eidx      = (const int*)d_in[1];   // [2,E] int32
    const float* elen      = (const float*)d_in[2];
    const float* W_in      = (const float*)d_in[3];
    const float* b_in      = (const float*)d_in[4];
    const float* att_k     = (const float*)d_in[5];
    const float* Wl        = (const float*)d_in[6]; // [2,128,128]
    const float* bl        = (const float*)d_in[7]; // [2,128]
    const float* gamma     = (const float*)d_in[8];
    const float* beta      = (const float*)d_in[9];

    float* h = (float*)d_out;                       // [N,128] reused as h buffer
    float* agg = (float*)d_ws;                      // [N,128]
    float* stats = agg + (size_t)N_NODES * HIDC;    // [256]

    proj_kernel<<<(N_NODES + 63) / 64, 256, 0, stream>>>(node_init, W_in, b_in, h);

    for (int l = 0; l < NLAYERS; ++l) {
        hipMemsetAsync(agg, 0, (size_t)N_NODES * HIDC * sizeof(float), stream);
        hipMemsetAsync(stats, 0, 2 * HIDC * sizeof(float), stream);
        edge_agg_kernel<<<(N_EDGES + 3) / 4, 256, 0, stream>>>(
            h, eidx, eidx + N_EDGES, elen, att_k, agg);
        dim3 ggrid((N_NODES + 63) / 64, 2);
        layer_gemm_kernel<<<ggrid, 256, 0, stream>>>(
            h, agg, Wl + (size_t)l * HIDC * HIDC, bl + (size_t)l * HIDC, stats);
        bn_kernel<<<N_NODES * (HIDC / 4) / 256, 256, 0, stream>>>(
            h, stats, gamma + (size_t)l * HIDC, beta + (size_t)l * HIDC);
    }
}

// Round 3
// 1266.837 us; speedup vs baseline: 1.1690x; 1.1690x over previous
//
#include <hip/hip_runtime.h>
#include <hip/hip_bf16.h>

#define N_NODES 300000
#define N_EDGES 600000
#define IN_DIMC 64
#define HIDC    128
#define NLAYERS 2
#define BN_EPS  1e-5f
#define INV_SQRT_H 0.08838834764831845f  // 1/sqrt(128)
#define NB_SCAN ((N_NODES + 255) / 256)  // 1172

typedef __bf16 bf16x8 __attribute__((ext_vector_type(8)));
typedef float floatx4 __attribute__((ext_vector_type(4)));

// ---------------------------------------------------------------------------
// Module-static scratch (keeps d_ws footprint to agg only = 153.6 MB, the
// size proven to fit in round 1).
// ---------------------------------------------------------------------------
__device__ int   g_row_ptr[N_NODES + 1];
__device__ int   g_cursor[N_NODES];
__device__ int   g_esrc[N_EDGES];
__device__ float g_einv[N_EDGES];
__device__ int   g_bsum[NB_SCAN];
__device__ __align__(16) __hip_bfloat16 g_Win_hi[128 * 64];
__device__ __align__(16) __hip_bfloat16 g_Win_lo[128 * 64];
__device__ __align__(16) __hip_bfloat16 g_Wl_hi[NLAYERS * 128 * 128];
__device__ __align__(16) __hip_bfloat16 g_Wl_lo[NLAYERS * 128 * 128];
__device__ float g_stats[NLAYERS * 2 * HIDC];

// split fp32 into hi+lo bf16 (combined ~2^-17 relative error)
__device__ inline void split2(float x, __hip_bfloat16& hi, __hip_bfloat16& lo) {
    hi = __float2bfloat16(x);
    lo = __float2bfloat16(x - __bfloat162float(hi));
}

// ---------------------------------------------------------------------------
__global__ void zero_kernel() {
    int i = blockIdx.x * 256 + threadIdx.x;
    if (i < N_NODES) g_cursor[i] = 0;
    if (i < NLAYERS * 2 * HIDC) g_stats[i] = 0.f;
}

// ---------------------------------------------------------------------------
// Weight prep: transpose to [n][k] (so MFMA B-fragments are 8 contiguous k)
// and split into hi/lo bf16.
// ---------------------------------------------------------------------------
__global__ void prep_w_kernel(const float* __restrict__ W_in,
                              const float* __restrict__ Wl)
{
    int id = blockIdx.x * 256 + threadIdx.x;
    if (id < 128 * 64) {
        int n = id >> 6, k = id & 63;
        split2(W_in[k * 128 + n], g_Win_hi[id], g_Win_lo[id]);
    }
    if (id < NLAYERS * 128 * 128) {
        int l = id >> 14, r = id & 16383;
        int n = r >> 7, k = r & 127;
        split2(Wl[l * 16384 + k * 128 + n], g_Wl_hi[id], g_Wl_lo[id]);
    }
}

// ---------------------------------------------------------------------------
// CSR build: hist -> scan -> scatter (edge source + 1/(1+len), dst-grouped)
// ---------------------------------------------------------------------------
__global__ void hist_kernel(const int* __restrict__ dst)
{
    int e = blockIdx.x * 256 + threadIdx.x;
    if (e < N_EDGES) atomicAdd(&g_cursor[dst[e]], 1);
}

__global__ void scan1_kernel()
{
    __shared__ int tmp[256];
    int t = threadIdx.x;
    int i = blockIdx.x * 256 + t;
    tmp[t] = (i < N_NODES) ? g_cursor[i] : 0;
    __syncthreads();
    for (int d = 128; d > 0; d >>= 1) {
        if (t < d) tmp[t] += tmp[t + d];
        __syncthreads();
    }
    if (t == 0) g_bsum[blockIdx.x] = tmp[0];
}

__global__ void scan2_kernel()
{
    __shared__ int tmp[256];
    __shared__ int carry;
    int t = threadIdx.x;
    if (t == 0) { carry = 0; g_row_ptr[N_NODES] = N_EDGES; }
    __syncthreads();
    for (int base = 0; base < NB_SCAN; base += 256) {
        int i = base + t;
        int v = (i < NB_SCAN) ? g_bsum[i] : 0;
        tmp[t] = v;
        __syncthreads();
        for (int d = 1; d < 256; d <<= 1) {
            int x = (t >= d) ? tmp[t - d] : 0;
            __syncthreads();
            tmp[t] += x;
            __syncthreads();
        }
        int c = carry;
        if (i < NB_SCAN) g_bsum[i] = c + tmp[t] - v;  // exclusive
        __syncthreads();
        if (t == 0) carry = c + tmp[255];
        __syncthreads();
    }
}

__global__ void scan3_kernel()
{
    __shared__ int tmp[256];
    int t = threadIdx.x;
    int i = blockIdx.x * 256 + t;
    int v = (i < N_NODES) ? g_cursor[i] : 0;
    tmp[t] = v;
    __syncthreads();
    for (int d = 1; d < 256; d <<= 1) {
        int x = (t >= d) ? tmp[t - d] : 0;
        __syncthreads();
        tmp[t] += x;
        __syncthreads();
    }
    int r = g_bsum[blockIdx.x] + tmp[t] - v;
    if (i < N_NODES) { g_row_ptr[i] = r; g_cursor[i] = r; }
}

__global__ void scatter_kernel(const int* __restrict__ src, const int* __restrict__ dst,
                               const float* __restrict__ elen)
{
    int e = blockIdx.x * 256 + threadIdx.x;
    if (e >= N_EDGES) return;
    int d = dst[e];
    int pos = atomicAdd(&g_cursor[d], 1);
    g_esrc[pos] = src[e];
    g_einv[pos] = 1.0f / (1.0f + elen[e]);
}

// ---------------------------------------------------------------------------
// edge_csr: one wave per dst node; lane covers channels {2l, 2l+1}.
// All math fp32. Stores relu(agg) as fp32. No atomics, no memsets.
// ---------------------------------------------------------------------------
__global__ __launch_bounds__(256) void edge_csr_kernel(
    const float* __restrict__ h, const float* __restrict__ att_k,
    float* __restrict__ agg)
{
    int lane = threadIdx.x & 63;
    int n = blockIdx.x * 4 + (threadIdx.x >> 6);
    if (n >= N_NODES) return;
    float2 ak = ((const float2*)att_k)[lane];
    int beg = g_row_ptr[n], end = g_row_ptr[n + 1];
    float a0 = 0.f, a1 = 0.f;
    for (int j = beg; j < end; ++j) {
        int s = g_esrc[j];
        float2 x = ((const float2*)(h + (size_t)s * HIDC))[lane];
        float p = x.x * ak.x + x.y * ak.y;
#pragma unroll
        for (int off = 32; off > 0; off >>= 1) p += __shfl_xor(p, off);
        float w = __expf(p * INV_SQRT_H) * g_einv[j];
        a0 += w * x.x;
        a1 += w * x.y;
    }
    float2 o;
    o.x = fmaxf(a0, 0.f);
    o.y = fmaxf(a1, 0.f);
    ((float2*)(agg + (size_t)n * HIDC))[lane] = o;
}

// ---------------------------------------------------------------------------
// proj: h[64 x 128] = X @ W_in + b via bf16x3 split MFMA (effectively fp32).
// LDS rows stride 72 bf16 (144 B): fragment b128 reads are 2-way (free).
// ---------------------------------------------------------------------------
__global__ __launch_bounds__(256) void proj_mfma_kernel(
    const float* __restrict__ X, const float* __restrict__ b,
    float* __restrict__ h)
{
    __shared__ __align__(16) __hip_bfloat16 Ah[64 * 72];
    __shared__ __align__(16) __hip_bfloat16 Al[64 * 72];
    __shared__ __align__(16) __hip_bfloat16 Bh[128 * 72];
    __shared__ __align__(16) __hip_bfloat16 Bl[128 * 72];
    int t = threadIdx.x;
    int nbase = blockIdx.x * 64;

    for (int i = t; i < 1024; i += 256) {            // B: 128 rows x 64 k
        int row = i >> 3, c8 = i & 7;
        *(float4*)((char*)Bh + row * 144 + c8 * 16) =
            *(const float4*)((const char*)g_Win_hi + row * 128 + c8 * 16);
        *(float4*)((char*)Bl + row * 144 + c8 * 16) =
            *(const float4*)((const char*)g_Win_lo + row * 128 + c8 * 16);
    }
    for (int i = t; i < 1024; i += 256) {            // A: 64 rows x 64 k fp32->split
        int row = i >> 4, c4 = i & 15;
        int n = nbase + row;
        float4 v = make_float4(0.f, 0.f, 0.f, 0.f);
        if (n < N_NODES) v = *(const float4*)(X + (size_t)n * IN_DIMC + c4 * 4);
        union { __hip_bfloat16 e[4]; uint2 u; } ph, pl;
        split2(v.x, ph.e[0], pl.e[0]); split2(v.y, ph.e[1], pl.e[1]);
        split2(v.z, ph.e[2], pl.e[2]); split2(v.w, ph.e[3], pl.e[3]);
        *(uint2*)((char*)Ah + row * 144 + c4 * 8) = ph.u;
        *(uint2*)((char*)Al + row * 144 + c4 * 8) = pl.u;
    }
    __syncthreads();

    int lane = t & 63, w = t >> 6;
    int m16 = lane & 15, quad = lane >> 4;
    floatx4 acc[8];
#pragma unroll
    for (int i = 0; i < 8; ++i) acc[i] = floatx4{0.f, 0.f, 0.f, 0.f};

#pragma unroll
    for (int kk = 0; kk < 64; kk += 32) {
        bf16x8 ah = *(const bf16x8*)((const char*)Ah + (w * 16 + m16) * 144 + (kk + quad * 8) * 2);
        bf16x8 al = *(const bf16x8*)((const char*)Al + (w * 16 + m16) * 144 + (kk + quad * 8) * 2);
#pragma unroll
        for (int nt = 0; nt < 8; ++nt) {
            bf16x8 bh = *(const bf16x8*)((const char*)Bh + (nt * 16 + m16) * 144 + (kk + quad * 8) * 2);
            bf16x8 bl = *(const bf16x8*)((const char*)Bl + (nt * 16 + m16) * 144 + (kk + quad * 8) * 2);
            acc[nt] = __builtin_amdgcn_mfma_f32_16x16x32_bf16(ah, bh, acc[nt], 0, 0, 0);
            acc[nt] = __builtin_amdgcn_mfma_f32_16x16x32_bf16(al, bh, acc[nt], 0, 0, 0);
            acc[nt] = __builtin_amdgcn_mfma_f32_16x16x32_bf16(ah, bl, acc[nt], 0, 0, 0);
        }
    }
#pragma unroll
    for (int nt = 0; nt < 8; ++nt) {
        int ch = nt * 16 + m16;
        float bias = b[ch];
#pragma unroll
        for (int r = 0; r < 4; ++r) {
            int n = nbase + w * 16 + quad * 4 + r;
            if (n < N_NODES) h[(size_t)n * HIDC + ch] = acc[nt][r] + bias;
        }
    }
}

// ---------------------------------------------------------------------------
// layer_gemm: h[64 x 128] += agg(fp32, relu'd) @ Wl + b via bf16x3 split MFMA.
// K=128 staged in halves of 64; BN stats accumulated to g_stats.
// LDS 56.3 KB -> 2 blocks/CU.
// ---------------------------------------------------------------------------
__global__ __launch_bounds__(256) void layer_gemm_kernel(
    float* __restrict__ h, const float* __restrict__ agg,
    const float* __restrict__ b, int layer)
{
    __shared__ __align__(16) __hip_bfloat16 Ah[64 * 72];
    __shared__ __align__(16) __hip_bfloat16 Al[64 * 72];
    __shared__ __align__(16) __hip_bfloat16 Bh[128 * 72];
    __shared__ __align__(16) __hip_bfloat16 Bl[128 * 72];
    __shared__ float red[256];
    int t = threadIdx.x;
    int nbase = blockIdx.x * 64;
    const __hip_bfloat16* Wh = g_Wl_hi + layer * 16384;
    const __hip_bfloat16* Wlo = g_Wl_lo + layer * 16384;
    red[t] = 0.f;

    int lane = t & 63, w = t >> 6;
    int m16 = lane & 15, quad = lane >> 4;
    floatx4 acc[8];
#pragma unroll
    for (int i = 0; i < 8; ++i) acc[i] = floatx4{0.f, 0.f, 0.f, 0.f};

    for (int kb = 0; kb < HIDC; kb += 64) {
        for (int i = t; i < 1024; i += 256) {        // B half: 128 rows x 64 k
            int row = i >> 3, c8 = i & 7;
            *(float4*)((char*)Bh + row * 144 + c8 * 16) =
                *(const float4*)((const char*)Wh + row * 256 + kb * 2 + c8 * 16);
            *(float4*)((char*)Bl + row * 144 + c8 * 16) =
                *(const float4*)((const char*)Wlo + row * 256 + kb * 2 + c8 * 16);
        }
        for (int i = t; i < 1024; i += 256) {        // A half: 64 rows x 64 k
            int row = i >> 4, c4 = i & 15;
            int n = nbase + row;
            float4 v = make_float4(0.f, 0.f, 0.f, 0.f);
            if (n < N_NODES) v = *(const float4*)(agg + (size_t)n * HIDC + kb + c4 * 4);
            union { __hip_bfloat16 e[4]; uint2 u; } ph, pl;
            split2(v.x, ph.e[0], pl.e[0]); split2(v.y, ph.e[1], pl.e[1]);
            split2(v.z, ph.e[2], pl.e[2]); split2(v.w, ph.e[3], pl.e[3]);
            *(uint2*)((char*)Ah + row * 144 + c4 * 8) = ph.u;
            *(uint2*)((char*)Al + row * 144 + c4 * 8) = pl.u;
        }
        __syncthreads();
#pragma unroll
        for (int kk = 0; kk < 64; kk += 32) {
            bf16x8 ah = *(const bf16x8*)((const char*)Ah + (w * 16 + m16) * 144 + (kk + quad * 8) * 2);
            bf16x8 al = *(const bf16x8*)((const char*)Al + (w * 16 + m16) * 144 + (kk + quad * 8) * 2);
#pragma unroll
            for (int nt = 0; nt < 8; ++nt) {
                bf16x8 bh = *(const bf16x8*)((const char*)Bh + (nt * 16 + m16) * 144 + (kk + quad * 8) * 2);
                bf16x8 bl = *(const bf16x8*)((const char*)Bl + (nt * 16 + m16) * 144 + (kk + quad * 8) * 2);
                acc[nt] = __builtin_amdgcn_mfma_f32_16x16x32_bf16(ah, bh, acc[nt], 0, 0, 0);
                acc[nt] = __builtin_amdgcn_mfma_f32_16x16x32_bf16(al, bh, acc[nt], 0, 0, 0);
                acc[nt] = __builtin_amdgcn_mfma_f32_16x16x32_bf16(ah, bl, acc[nt], 0, 0, 0);
            }
        }
        __syncthreads();
    }

#pragma unroll
    for (int nt = 0; nt < 8; ++nt) {
        int ch = nt * 16 + m16;
        float bias = b[ch];
        float s = 0.f, q = 0.f;
#pragma unroll
        for (int r = 0; r < 4; ++r) {
            int n = nbase + w * 16 + quad * 4 + r;
            if (n < N_NODES) {
                float* hp = h + (size_t)n * HIDC + ch;
                float o = *hp + acc[nt][r] + bias;
                *hp = o;
                s += o; q += o * o;
            }
        }
        s += __shfl_xor(s, 16); s += __shfl_xor(s, 32);
        q += __shfl_xor(q, 16); q += __shfl_xor(q, 32);
        if (quad == 0) {
            atomicAdd(&red[ch], s);
            atomicAdd(&red[HIDC + ch], q);
        }
    }
    __syncthreads();
    atomicAdd(&g_stats[layer * 2 * HIDC + t], red[t]);
}

// ---------------------------------------------------------------------------
// bn_apply: h = (h - mean) * rsqrt(var + eps) * gamma + beta
// ---------------------------------------------------------------------------
__global__ __launch_bounds__(256) void bn_kernel(
    float* __restrict__ h, int layer,
    const float* __restrict__ gamma, const float* __restrict__ beta)
{
    const float invN = 1.0f / (float)N_NODES;
    const float* stats = g_stats + layer * 2 * HIDC;
    size_t idx = (size_t)blockIdx.x * 256 + threadIdx.x;  // float4 index
    if (idx >= (size_t)N_NODES * (HIDC / 4)) return;
    int cg = (int)(idx & 31);
    float4 s1 = ((const float4*)stats)[cg];
    float4 s2 = ((const float4*)(stats + HIDC))[cg];
    float4 g = ((const float4*)gamma)[cg];
    float4 be = ((const float4*)beta)[cg];
    float4 mean, sc;
    mean.x = s1.x * invN; mean.y = s1.y * invN;
    mean.z = s1.z * invN; mean.w = s1.w * invN;
    sc.x = g.x * rsqrtf(s2.x * invN - mean.x * mean.x + BN_EPS);
    sc.y = g.y * rsqrtf(s2.y * invN - mean.y * mean.y + BN_EPS);
    sc.z = g.z * rsqrtf(s2.z * invN - mean.z * mean.z + BN_EPS);
    sc.w = g.w * rsqrtf(s2.w * invN - mean.w * mean.w + BN_EPS);
    float4 v = ((float4*)h)[idx];
    v.x = (v.x - mean.x) * sc.x + be.x;
    v.y = (v.y - mean.y) * sc.y + be.y;
    v.z = (v.z - mean.z) * sc.z + be.z;
    v.w = (v.w - mean.w) * sc.w + be.w;
    ((float4*)h)[idx] = v;
}

// ---------------------------------------------------------------------------
extern "C" void kernel_launch(void* const* d_in, const int* in_sizes, int n_in,
                              void* d_out, int out_size, void* d_ws, size_t ws_size,
                              hipStream_t stream) {
    (void)in_sizes; (void)n_in; (void)out_size; (void)ws_size;
    const float* node_init = (const float*)d_in[0];
    const int*   eidx      = (const int*)d_in[1];   // [2,E] int32
    const float* elen      = (const float*)d_in[2];
    const float* W_in      = (const float*)d_in[3];
    const float* b_in      = (const float*)d_in[4];
    const float* att_k     = (const float*)d_in[5];
    const float* Wl        = (const float*)d_in[6]; // [2,128,128]
    const float* bl        = (const float*)d_in[7]; // [2,128]
    const float* gamma     = (const float*)d_in[8];
    const float* beta      = (const float*)d_in[9];

    float* h   = (float*)d_out;  // [N,128]
    float* agg = (float*)d_ws;   // [N,128] fp32 (only ws use: 153.6 MB)

    const int* src = eidx;
    const int* dst = eidx + N_EDGES;

    zero_kernel<<<NB_SCAN, 256, 0, stream>>>();
    hist_kernel<<<(N_EDGES + 255) / 256, 256, 0, stream>>>(dst);
    scan1_kernel<<<NB_SCAN, 256, 0, stream>>>();
    scan2_kernel<<<1, 256, 0, stream>>>();
    scan3_kernel<<<NB_SCAN, 256, 0, stream>>>();
    scatter_kernel<<<(N_EDGES + 255) / 256, 256, 0, stream>>>(src, dst, elen);
    prep_w_kernel<<<(NLAYERS * 128 * 128 + 255) / 256, 256, 0, stream>>>(W_in, Wl);

    proj_mfma_kernel<<<(N_NODES + 63) / 64, 256, 0, stream>>>(node_init, b_in, h);

    for (int l = 0; l < NLAYERS; ++l) {
        edge_csr_kernel<<<(N_NODES + 3) / 4, 256, 0, stream>>>(h, att_k, agg);
        layer_gemm_kernel<<<(N_NODES + 63) / 64, 256, 0, stream>>>(
            h, agg, bl + (size_t)l * HIDC, l);
        bn_kernel<<<N_NODES * (HIDC / 4) / 256, 256, 0, stream>>>(
            h, l, gamma + (size_t)l * HIDC, beta + (size_t)l * HIDC);
    }
}

// Round 4
// 958.444 us; speedup vs baseline: 1.5451x; 1.3218x over previous
//
#include <hip/hip_runtime.h>
#include <hip/hip_bf16.h>

#define N_NODES 300000
#define N_EDGES 600000
#define IN_DIMC 64
#define HIDC    128
#define NLAYERS 2
#define BN_EPS  1e-5f
#define INV_SQRT_H 0.08838834764831845f  // 1/sqrt(128)
#define NB_SCAN ((N_NODES + 255) / 256)  // 1172
#define NTILES  (N_NODES / 16)           // 18750 (exact)

typedef __bf16 bf16x8 __attribute__((ext_vector_type(8)));
typedef float floatx4 __attribute__((ext_vector_type(4)));

// ---------------------------------------------------------------------------
// Module-static scratch; d_ws holds only fp32 agg (153.6 MB, proven to fit).
// ---------------------------------------------------------------------------
__device__ int   g_row_ptr[N_NODES + 1];
__device__ int   g_cursor[N_NODES];
__device__ int   g_esrc[N_EDGES];
__device__ float g_einv[N_EDGES];
__device__ int   g_bsum[NB_SCAN];
__device__ __align__(16) __hip_bfloat16 g_Win_hi[128 * 64];
__device__ __align__(16) __hip_bfloat16 g_Win_lo[128 * 64];
__device__ __align__(16) __hip_bfloat16 g_Wl_hi[NLAYERS * 128 * 128];
__device__ __align__(16) __hip_bfloat16 g_Wl_lo[NLAYERS * 128 * 128];
__device__ float g_stats[NLAYERS * 2 * HIDC];   // per layer: [sum(128) | sumsq(128)]
__device__ __align__(16) float g_bn_sc[NLAYERS * HIDC];
__device__ __align__(16) float g_bn_sh[NLAYERS * HIDC];

// split fp32 into hi+lo bf16 (combined ~2^-17 relative error)
__device__ inline void split2(float x, __hip_bfloat16& hi, __hip_bfloat16& lo) {
    hi = __float2bfloat16(x);
    lo = __float2bfloat16(x - __bfloat162float(hi));
}

// ---------------------------------------------------------------------------
__global__ void zero_kernel() {
    int i = blockIdx.x * 256 + threadIdx.x;
    if (i < N_NODES) g_cursor[i] = 0;
    if (i < NLAYERS * 2 * HIDC) g_stats[i] = 0.f;
}

// ---------------------------------------------------------------------------
// Weight prep: transpose to [n][k] (MFMA B-fragments = 8 contiguous k), split.
// ---------------------------------------------------------------------------
__global__ void prep_w_kernel(const float* __restrict__ W_in,
                              const float* __restrict__ Wl)
{
    int id = blockIdx.x * 256 + threadIdx.x;
    if (id < 128 * 64) {
        int n = id >> 6, k = id & 63;
        split2(W_in[k * 128 + n], g_Win_hi[id], g_Win_lo[id]);
    }
    if (id < NLAYERS * 128 * 128) {
        int l = id >> 14, r = id & 16383;
        int n = r >> 7, k = r & 127;
        split2(Wl[l * 16384 + k * 128 + n], g_Wl_hi[id], g_Wl_lo[id]);
    }
}

// ---------------------------------------------------------------------------
// CSR build: hist -> scan -> scatter
// ---------------------------------------------------------------------------
__global__ void hist_kernel(const int* __restrict__ dst)
{
    int e = blockIdx.x * 256 + threadIdx.x;
    if (e < N_EDGES) atomicAdd(&g_cursor[dst[e]], 1);
}

__global__ void scan1_kernel()
{
    __shared__ int tmp[256];
    int t = threadIdx.x;
    int i = blockIdx.x * 256 + t;
    tmp[t] = (i < N_NODES) ? g_cursor[i] : 0;
    __syncthreads();
    for (int d = 128; d > 0; d >>= 1) {
        if (t < d) tmp[t] += tmp[t + d];
        __syncthreads();
    }
    if (t == 0) g_bsum[blockIdx.x] = tmp[0];
}

__global__ void scan2_kernel()
{
    __shared__ int tmp[256];
    __shared__ int carry;
    int t = threadIdx.x;
    if (t == 0) { carry = 0; g_row_ptr[N_NODES] = N_EDGES; }
    __syncthreads();
    for (int base = 0; base < NB_SCAN; base += 256) {
        int i = base + t;
        int v = (i < NB_SCAN) ? g_bsum[i] : 0;
        tmp[t] = v;
        __syncthreads();
        for (int d = 1; d < 256; d <<= 1) {
            int x = (t >= d) ? tmp[t - d] : 0;
            __syncthreads();
            tmp[t] += x;
            __syncthreads();
        }
        int c = carry;
        if (i < NB_SCAN) g_bsum[i] = c + tmp[t] - v;  // exclusive
        __syncthreads();
        if (t == 0) carry = c + tmp[255];
        __syncthreads();
    }
}

__global__ void scan3_kernel()
{
    __shared__ int tmp[256];
    int t = threadIdx.x;
    int i = blockIdx.x * 256 + t;
    int v = (i < N_NODES) ? g_cursor[i] : 0;
    tmp[t] = v;
    __syncthreads();
    for (int d = 1; d < 256; d <<= 1) {
        int x = (t >= d) ? tmp[t - d] : 0;
        __syncthreads();
        tmp[t] += x;
        __syncthreads();
    }
    int r = g_bsum[blockIdx.x] + tmp[t] - v;
    if (i < N_NODES) { g_row_ptr[i] = r; g_cursor[i] = r; }
}

__global__ void scatter_kernel(const int* __restrict__ src, const int* __restrict__ dst,
                               const float* __restrict__ elen)
{
    int e = blockIdx.x * 256 + threadIdx.x;
    if (e >= N_EDGES) return;
    int d = dst[e];
    int pos = atomicAdd(&g_cursor[d], 1);
    g_esrc[pos] = src[e];
    g_einv[pos] = 1.0f / (1.0f + elen[e]);
}

// ---------------------------------------------------------------------------
// edge_csr: one wave per dst node; lane covers channels {2l, 2l+1}.
// Applies previous layer's BN (identity for layer 0) to gathered rows inline.
// ---------------------------------------------------------------------------
__global__ __launch_bounds__(256) void edge_csr_kernel(
    const float* __restrict__ h, const float* __restrict__ att_k,
    float* __restrict__ agg, int prev)
{
    int lane = threadIdx.x & 63;
    int n = blockIdx.x * 4 + (threadIdx.x >> 6);
    if (n >= N_NODES) return;
    float2 ak = ((const float2*)att_k)[lane];
    float2 sc = make_float2(1.f, 1.f), sh = make_float2(0.f, 0.f);
    if (prev >= 0) {
        sc = ((const float2*)(g_bn_sc + prev * HIDC))[lane];
        sh = ((const float2*)(g_bn_sh + prev * HIDC))[lane];
    }
    int beg = g_row_ptr[n], end = g_row_ptr[n + 1];
    float a0 = 0.f, a1 = 0.f;
    for (int j = beg; j < end; ++j) {
        int s = g_esrc[j];
        float2 x = ((const float2*)(h + (size_t)s * HIDC))[lane];
        x.x = sc.x * x.x + sh.x;
        x.y = sc.y * x.y + sh.y;
        float p = x.x * ak.x + x.y * ak.y;
#pragma unroll
        for (int off = 32; off > 0; off >>= 1) p += __shfl_xor(p, off);
        float w = __expf(p * INV_SQRT_H) * g_einv[j];
        a0 += w * x.x;
        a1 += w * x.y;
    }
    float2 o;
    o.x = fmaxf(a0, 0.f);
    o.y = fmaxf(a1, 0.f);
    ((float2*)(agg + (size_t)n * HIDC))[lane] = o;
}

// ---------------------------------------------------------------------------
// proj: h[64 x 128] = X @ W_in + b via bf16x3 split MFMA (effectively fp32).
// ---------------------------------------------------------------------------
__global__ __launch_bounds__(256) void proj_mfma_kernel(
    const float* __restrict__ X, const float* __restrict__ b,
    float* __restrict__ h)
{
    __shared__ __align__(16) __hip_bfloat16 Ah[64 * 72];
    __shared__ __align__(16) __hip_bfloat16 Al[64 * 72];
    __shared__ __align__(16) __hip_bfloat16 Bh[128 * 72];
    __shared__ __align__(16) __hip_bfloat16 Bl[128 * 72];
    int t = threadIdx.x;
    int nbase = blockIdx.x * 64;

    for (int i = t; i < 1024; i += 256) {            // B: 128 rows x 64 k
        int row = i >> 3, c8 = i & 7;
        *(float4*)((char*)Bh + row * 144 + c8 * 16) =
            *(const float4*)((const char*)g_Win_hi + row * 128 + c8 * 16);
        *(float4*)((char*)Bl + row * 144 + c8 * 16) =
            *(const float4*)((const char*)g_Win_lo + row * 128 + c8 * 16);
    }
    for (int i = t; i < 1024; i += 256) {            // A: 64 rows x 64 k
        int row = i >> 4, c4 = i & 15;
        int n = nbase + row;
        float4 v = make_float4(0.f, 0.f, 0.f, 0.f);
        if (n < N_NODES) v = *(const float4*)(X + (size_t)n * IN_DIMC + c4 * 4);
        union { __hip_bfloat16 e[4]; uint2 u; } ph, pl;
        split2(v.x, ph.e[0], pl.e[0]); split2(v.y, ph.e[1], pl.e[1]);
        split2(v.z, ph.e[2], pl.e[2]); split2(v.w, ph.e[3], pl.e[3]);
        *(uint2*)((char*)Ah + row * 144 + c4 * 8) = ph.u;
        *(uint2*)((char*)Al + row * 144 + c4 * 8) = pl.u;
    }
    __syncthreads();

    int lane = t & 63, w = t >> 6;
    int m16 = lane & 15, quad = lane >> 4;
    floatx4 acc[8];
#pragma unroll
    for (int i = 0; i < 8; ++i) acc[i] = floatx4{0.f, 0.f, 0.f, 0.f};

#pragma unroll
    for (int kk = 0; kk < 64; kk += 32) {
        bf16x8 ah = *(const bf16x8*)((const char*)Ah + (w * 16 + m16) * 144 + (kk + quad * 8) * 2);
        bf16x8 al = *(const bf16x8*)((const char*)Al + (w * 16 + m16) * 144 + (kk + quad * 8) * 2);
#pragma unroll
        for (int nt = 0; nt < 8; ++nt) {
            bf16x8 bh = *(const bf16x8*)((const char*)Bh + (nt * 16 + m16) * 144 + (kk + quad * 8) * 2);
            bf16x8 bl = *(const bf16x8*)((const char*)Bl + (nt * 16 + m16) * 144 + (kk + quad * 8) * 2);
            acc[nt] = __builtin_amdgcn_mfma_f32_16x16x32_bf16(ah, bh, acc[nt], 0, 0, 0);
            acc[nt] = __builtin_amdgcn_mfma_f32_16x16x32_bf16(al, bh, acc[nt], 0, 0, 0);
            acc[nt] = __builtin_amdgcn_mfma_f32_16x16x32_bf16(ah, bl, acc[nt], 0, 0, 0);
        }
    }
#pragma unroll
    for (int nt = 0; nt < 8; ++nt) {
        int ch = nt * 16 + m16;
        float bias = b[ch];
#pragma unroll
        for (int r = 0; r < 4; ++r) {
            int n = nbase + w * 16 + quad * 4 + r;
            if (n < N_NODES) h[(size_t)n * HIDC + ch] = acc[nt][r] + bias;
        }
    }
}

// ---------------------------------------------------------------------------
// layer_gemm v2: stage B (hi+lo, 69.6KB) ONCE, then waves grid-stride over
// independent 16-node tiles. A fragments come straight from global (agg rows
// are 8-contiguous-fp32 per lane = the MFMA A layout) -> no barriers in loop.
// Epilogue: h_new = bn_prev(h_old) + acc + bias; BN stats in registers.
// ---------------------------------------------------------------------------
__global__ __launch_bounds__(256) void layer_gemm_kernel(
    float* __restrict__ h, const float* __restrict__ agg,
    const float* __restrict__ b, int layer, int prev)
{
    __shared__ __align__(16) __hip_bfloat16 Bh[128 * 136];
    __shared__ __align__(16) __hip_bfloat16 Bl[128 * 136];
    __shared__ float red[256];
    int t = threadIdx.x;
    const __hip_bfloat16* Wh = g_Wl_hi + layer * 16384;
    const __hip_bfloat16* Wlo = g_Wl_lo + layer * 16384;
    red[t] = 0.f;

    for (int i = t; i < 2048; i += 256) {      // B: [n=128][k=128], stride 272B
        int row = i >> 4, c8 = i & 15;
        *(float4*)((char*)Bh + row * 272 + c8 * 16) =
            *(const float4*)((const char*)Wh + row * 256 + c8 * 16);
        *(float4*)((char*)Bl + row * 272 + c8 * 16) =
            *(const float4*)((const char*)Wlo + row * 256 + c8 * 16);
    }
    __syncthreads();

    const int lane = t & 63, w = t >> 6;
    const int m16 = lane & 15, quad = lane >> 4;
    const int wid = blockIdx.x * 4 + w;
    const int nwaves = gridDim.x * 4;

    // per-lane channel constants (ch = nt*16 + m16), tile-invariant
    float bias[8], scp[8], shp[8];
#pragma unroll
    for (int nt = 0; nt < 8; ++nt) {
        int ch = nt * 16 + m16;
        bias[nt] = b[ch];
        scp[nt] = (prev >= 0) ? g_bn_sc[prev * HIDC + ch] : 1.f;
        shp[nt] = (prev >= 0) ? g_bn_sh[prev * HIDC + ch] : 0.f;
    }
    float sreg[8], qreg[8];
#pragma unroll
    for (int nt = 0; nt < 8; ++nt) { sreg[nt] = 0.f; qreg[nt] = 0.f; }

    for (int tile = wid; tile < NTILES; tile += nwaves) {
        const float* arow = agg + (size_t)(tile * 16 + m16) * HIDC + quad * 8;
        floatx4 acc[8];
#pragma unroll
        for (int i = 0; i < 8; ++i) acc[i] = floatx4{0.f, 0.f, 0.f, 0.f};

#pragma unroll
        for (int kk = 0; kk < 4; ++kk) {
            float4 a0 = *(const float4*)(arow + kk * 32);
            float4 a1 = *(const float4*)(arow + kk * 32 + 4);
            union { __hip_bfloat16 e[8]; bf16x8 v; } ah, al;
            split2(a0.x, ah.e[0], al.e[0]); split2(a0.y, ah.e[1], al.e[1]);
            split2(a0.z, ah.e[2], al.e[2]); split2(a0.w, ah.e[3], al.e[3]);
            split2(a1.x, ah.e[4], al.e[4]); split2(a1.y, ah.e[5], al.e[5]);
            split2(a1.z, ah.e[6], al.e[6]); split2(a1.w, ah.e[7], al.e[7]);
#pragma unroll
            for (int nt = 0; nt < 8; ++nt) {
                const char* bp = (const char*)Bh + (nt * 16 + m16) * 272 + (kk * 32 + quad * 8) * 2;
                const char* lp = (const char*)Bl + (nt * 16 + m16) * 272 + (kk * 32 + quad * 8) * 2;
                bf16x8 bh = *(const bf16x8*)bp;
                bf16x8 bl = *(const bf16x8*)lp;
                acc[nt] = __builtin_amdgcn_mfma_f32_16x16x32_bf16(ah.v, bh, acc[nt], 0, 0, 0);
                acc[nt] = __builtin_amdgcn_mfma_f32_16x16x32_bf16(al.v, bh, acc[nt], 0, 0, 0);
                acc[nt] = __builtin_amdgcn_mfma_f32_16x16x32_bf16(ah.v, bl, acc[nt], 0, 0, 0);
            }
        }
        // epilogue: D row = quad*4+r (node), col = m16 (+16*nt) (channel)
        int node0 = tile * 16 + quad * 4;
#pragma unroll
        for (int nt = 0; nt < 8; ++nt) {
            int ch = nt * 16 + m16;
#pragma unroll
            for (int r = 0; r < 4; ++r) {
                float* hp = h + (size_t)(node0 + r) * HIDC + ch;
                float o = scp[nt] * (*hp) + shp[nt] + acc[nt][r] + bias[nt];
                *hp = o;
                sreg[nt] += o;
                qreg[nt] += o * o;
            }
        }
    }

    // reduce stats: across quads -> LDS -> global
#pragma unroll
    for (int nt = 0; nt < 8; ++nt) {
        float s = sreg[nt], q = qreg[nt];
        s += __shfl_xor(s, 16); s += __shfl_xor(s, 32);
        q += __shfl_xor(q, 16); q += __shfl_xor(q, 32);
        if (quad == 0) {
            atomicAdd(&red[nt * 16 + m16], s);
            atomicAdd(&red[HIDC + nt * 16 + m16], q);
        }
    }
    __syncthreads();
    atomicAdd(&g_stats[layer * 2 * HIDC + t], red[t]);
}

// ---------------------------------------------------------------------------
// bn_prep: stats -> scale/shift (1 block, 128 threads)
// ---------------------------------------------------------------------------
__global__ void bn_prep_kernel(const float* __restrict__ gamma,
                               const float* __restrict__ beta, int layer)
{
    int c = threadIdx.x;
    if (c >= HIDC) return;
    const float invN = 1.0f / (float)N_NODES;
    float mean = g_stats[layer * 2 * HIDC + c] * invN;
    float var = g_stats[layer * 2 * HIDC + HIDC + c] * invN - mean * mean;
    float s = gamma[layer * HIDC + c] * rsqrtf(var + BN_EPS);
    g_bn_sc[layer * HIDC + c] = s;
    g_bn_sh[layer * HIDC + c] = beta[layer * HIDC + c] - mean * s;
}

// ---------------------------------------------------------------------------
// bn_apply (final output only): h = sc*h + sh
// ---------------------------------------------------------------------------
__global__ __launch_bounds__(256) void bn_apply_kernel(float* __restrict__ h, int layer)
{
    size_t idx = (size_t)blockIdx.x * 256 + threadIdx.x;  // float4 index
    if (idx >= (size_t)N_NODES * (HIDC / 4)) return;
    int cg = (int)(idx & 31);
    float4 sc = ((const float4*)(g_bn_sc + layer * HIDC))[cg];
    float4 sh = ((const float4*)(g_bn_sh + layer * HIDC))[cg];
    float4 v = ((float4*)h)[idx];
    v.x = sc.x * v.x + sh.x;
    v.y = sc.y * v.y + sh.y;
    v.z = sc.z * v.z + sh.z;
    v.w = sc.w * v.w + sh.w;
    ((float4*)h)[idx] = v;
}

// ---------------------------------------------------------------------------
extern "C" void kernel_launch(void* const* d_in, const int* in_sizes, int n_in,
                              void* d_out, int out_size, void* d_ws, size_t ws_size,
                              hipStream_t stream) {
    (void)in_sizes; (void)n_in; (void)out_size; (void)ws_size;
    const float* node_init = (const float*)d_in[0];
    const int*   eidx      = (const int*)d_in[1];   // [2,E] int32
    const float* elen      = (const float*)d_in[2];
    const float* W_in      = (const float*)d_in[3];
    const float* b_in      = (const float*)d_in[4];
    const float* att_k     = (const float*)d_in[5];
    const float* Wl        = (const float*)d_in[6]; // [2,128,128]
    const float* bl        = (const float*)d_in[7]; // [2,128]
    const float* gamma     = (const float*)d_in[8];
    const float* beta      = (const float*)d_in[9];

    float* h   = (float*)d_out;  // [N,128]
    float* agg = (float*)d_ws;   // [N,128] fp32

    const int* src = eidx;
    const int* dst = eidx + N_EDGES;

    zero_kernel<<<NB_SCAN, 256, 0, stream>>>();
    hist_kernel<<<(N_EDGES + 255) / 256, 256, 0, stream>>>(dst);
    scan1_kernel<<<NB_SCAN, 256, 0, stream>>>();
    scan2_kernel<<<1, 256, 0, stream>>>();
    scan3_kernel<<<NB_SCAN, 256, 0, stream>>>();
    scatter_kernel<<<(N_EDGES + 255) / 256, 256, 0, stream>>>(src, dst, elen);
    prep_w_kernel<<<(NLAYERS * 128 * 128 + 255) / 256, 256, 0, stream>>>(W_in, Wl);

    proj_mfma_kernel<<<(N_NODES + 63) / 64, 256, 0, stream>>>(node_init, b_in, h);

    for (int l = 0; l < NLAYERS; ++l) {
        edge_csr_kernel<<<(N_NODES + 3) / 4, 256, 0, stream>>>(h, att_k, agg, l - 1);
        layer_gemm_kernel<<<512, 256, 0, stream>>>(h, agg, bl + (size_t)l * HIDC, l, l - 1);
        bn_prep_kernel<<<1, 128, 0, stream>>>(gamma, beta, l);
    }
    bn_apply_kernel<<<(N_NODES * (HIDC / 4) + 255) / 256, 256, 0, stream>>>(h, NLAYERS - 1);
}

// Round 5
// 942.378 us; speedup vs baseline: 1.5714x; 1.0170x over previous
//
#include <hip/hip_runtime.h>
#include <hip/hip_bf16.h>

#define N_NODES 300000
#define N_EDGES 600000
#define IN_DIMC 64
#define HIDC    128
#define NLAYERS 2
#define BN_EPS  1e-5f
#define INV_SQRT_H 0.08838834764831845f  // 1/sqrt(128)
#define NB_SCAN ((N_NODES + 255) / 256)  // 1172
#define NTILES  (N_NODES / 16)           // 18750 (exact)

typedef __bf16 bf16x8 __attribute__((ext_vector_type(8)));
typedef float floatx4 __attribute__((ext_vector_type(4)));

// ---------------------------------------------------------------------------
// Module-static scratch; d_ws holds only fp32 agg (153.6 MB, proven to fit).
// ---------------------------------------------------------------------------
__device__ int   g_row_ptr[N_NODES + 1];
__device__ int   g_cursor[N_NODES];
__device__ __align__(8) int2 g_edge[N_EDGES];   // x = src, y = bits(1/(1+len))
__device__ int   g_bsum[NB_SCAN];
__device__ float g_ekey[N_NODES];               // exp(key) per src node
__device__ __align__(16) __hip_bfloat16 g_Win_hi[128 * 64];
__device__ __align__(16) __hip_bfloat16 g_Win_lo[128 * 64];
__device__ __align__(16) __hip_bfloat16 g_Wl_hi[NLAYERS * 128 * 128];
__device__ __align__(16) __hip_bfloat16 g_Wl_lo[NLAYERS * 128 * 128];
__device__ float g_stats[NLAYERS * 2 * HIDC];   // per layer: [sum(128) | sumsq(128)]
__device__ __align__(16) float g_bn_sc[NLAYERS * HIDC];
__device__ __align__(16) float g_bn_sh[NLAYERS * HIDC];

// split fp32 into hi+lo bf16 (combined ~2^-17 relative error)
__device__ inline void split2(float x, __hip_bfloat16& hi, __hip_bfloat16& lo) {
    hi = __float2bfloat16(x);
    lo = __float2bfloat16(x - __bfloat162float(hi));
}

// ---------------------------------------------------------------------------
__global__ void zero_kernel() {
    int i = blockIdx.x * 256 + threadIdx.x;
    if (i < N_NODES) g_cursor[i] = 0;
    if (i < NLAYERS * 2 * HIDC) g_stats[i] = 0.f;
}

// ---------------------------------------------------------------------------
// Weight prep: transpose to [n][k] (MFMA B-fragments = 8 contiguous k), split.
// ---------------------------------------------------------------------------
__global__ void prep_w_kernel(const float* __restrict__ W_in,
                              const float* __restrict__ Wl)
{
    int id = blockIdx.x * 256 + threadIdx.x;
    if (id < 128 * 64) {
        int n = id >> 6, k = id & 63;
        split2(W_in[k * 128 + n], g_Win_hi[id], g_Win_lo[id]);
    }
    if (id < NLAYERS * 128 * 128) {
        int l = id >> 14, r = id & 16383;
        int n = r >> 7, k = r & 127;
        split2(Wl[l * 16384 + k * 128 + n], g_Wl_hi[id], g_Wl_lo[id]);
    }
}

// ---------------------------------------------------------------------------
// CSR build: hist -> scan -> scatter (packed src + inv-len per edge)
// ---------------------------------------------------------------------------
__global__ void hist_kernel(const int* __restrict__ dst)
{
    int e = blockIdx.x * 256 + threadIdx.x;
    if (e < N_EDGES) atomicAdd(&g_cursor[dst[e]], 1);
}

__global__ void scan1_kernel()
{
    __shared__ int tmp[256];
    int t = threadIdx.x;
    int i = blockIdx.x * 256 + t;
    tmp[t] = (i < N_NODES) ? g_cursor[i] : 0;
    __syncthreads();
    for (int d = 128; d > 0; d >>= 1) {
        if (t < d) tmp[t] += tmp[t + d];
        __syncthreads();
    }
    if (t == 0) g_bsum[blockIdx.x] = tmp[0];
}

__global__ void scan2_kernel()
{
    __shared__ int tmp[256];
    __shared__ int carry;
    int t = threadIdx.x;
    if (t == 0) { carry = 0; g_row_ptr[N_NODES] = N_EDGES; }
    __syncthreads();
    for (int base = 0; base < NB_SCAN; base += 256) {
        int i = base + t;
        int v = (i < NB_SCAN) ? g_bsum[i] : 0;
        tmp[t] = v;
        __syncthreads();
        for (int d = 1; d < 256; d <<= 1) {
            int x = (t >= d) ? tmp[t - d] : 0;
            __syncthreads();
            tmp[t] += x;
            __syncthreads();
        }
        int c = carry;
        if (i < NB_SCAN) g_bsum[i] = c + tmp[t] - v;  // exclusive
        __syncthreads();
        if (t == 0) carry = c + tmp[255];
        __syncthreads();
    }
}

__global__ void scan3_kernel()
{
    __shared__ int tmp[256];
    int t = threadIdx.x;
    int i = blockIdx.x * 256 + t;
    int v = (i < N_NODES) ? g_cursor[i] : 0;
    tmp[t] = v;
    __syncthreads();
    for (int d = 1; d < 256; d <<= 1) {
        int x = (t >= d) ? tmp[t - d] : 0;
        __syncthreads();
        tmp[t] += x;
        __syncthreads();
    }
    int r = g_bsum[blockIdx.x] + tmp[t] - v;
    if (i < N_NODES) { g_row_ptr[i] = r; g_cursor[i] = r; }
}

__global__ void scatter_kernel(const int* __restrict__ src, const int* __restrict__ dst,
                               const float* __restrict__ elen)
{
    int e = blockIdx.x * 256 + threadIdx.x;
    if (e >= N_EDGES) return;
    int d = dst[e];
    int pos = atomicAdd(&g_cursor[d], 1);
    int2 ed;
    ed.x = src[e];
    ed.y = __float_as_int(1.0f / (1.0f + elen[e]));
    g_edge[pos] = ed;
}

// ---------------------------------------------------------------------------
// edge_csr v2: one wave per dst node; lane covers channels {2l, 2l+1}.
// Keys precomputed per src node (g_ekey) -> inner loop is pure gather+FMA,
// no shuffles/exp. BN fold via sum-of-weights trick in epilogue.
// ---------------------------------------------------------------------------
__global__ __launch_bounds__(256) void edge_csr_kernel(
    const float* __restrict__ h, float* __restrict__ agg, int prev)
{
    int lane = threadIdx.x & 63;
    int n = blockIdx.x * 4 + (threadIdx.x >> 6);
    if (n >= N_NODES) return;
    int beg = g_row_ptr[n], end = g_row_ptr[n + 1];
    float a0 = 0.f, a1 = 0.f, sw = 0.f;
    const float2* h2 = (const float2*)h;
    int j = beg;
    for (; j + 1 < end; j += 2) {
        int2 e0 = g_edge[j];
        int2 e1 = g_edge[j + 1];
        float w0 = g_ekey[e0.x] * __int_as_float(e0.y);
        float w1 = g_ekey[e1.x] * __int_as_float(e1.y);
        float2 x0 = h2[(size_t)e0.x * 64 + lane];
        float2 x1 = h2[(size_t)e1.x * 64 + lane];
        a0 += w0 * x0.x + w1 * x1.x;
        a1 += w0 * x0.y + w1 * x1.y;
        sw += w0 + w1;
    }
    if (j < end) {
        int2 e0 = g_edge[j];
        float w0 = g_ekey[e0.x] * __int_as_float(e0.y);
        float2 x0 = h2[(size_t)e0.x * 64 + lane];
        a0 += w0 * x0.x;
        a1 += w0 * x0.y;
        sw += w0;
    }
    float2 sc = make_float2(1.f, 1.f), sh = make_float2(0.f, 0.f);
    if (prev >= 0) {
        sc = ((const float2*)(g_bn_sc + prev * HIDC))[lane];
        sh = ((const float2*)(g_bn_sh + prev * HIDC))[lane];
    }
    float2 o;
    o.x = fmaxf(sc.x * a0 + sh.x * sw, 0.f);
    o.y = fmaxf(sc.y * a1 + sh.y * sw, 0.f);
    ((float2*)(agg + (size_t)n * HIDC))[lane] = o;
}

// ---------------------------------------------------------------------------
// proj: h[64 x 128] = X @ W_in + b via bf16x3 split MFMA; epilogue also emits
// g_ekey[n] = exp(dot(h[n], att_k) / sqrt(H)) for layer 0 (no BN before it).
// ---------------------------------------------------------------------------
__global__ __launch_bounds__(256) void proj_mfma_kernel(
    const float* __restrict__ X, const float* __restrict__ b,
    const float* __restrict__ att_k, float* __restrict__ h)
{
    __shared__ __align__(16) __hip_bfloat16 Ah[64 * 72];
    __shared__ __align__(16) __hip_bfloat16 Al[64 * 72];
    __shared__ __align__(16) __hip_bfloat16 Bh[128 * 72];
    __shared__ __align__(16) __hip_bfloat16 Bl[128 * 72];
    int t = threadIdx.x;
    int nbase = blockIdx.x * 64;

    for (int i = t; i < 1024; i += 256) {            // B: 128 rows x 64 k
        int row = i >> 3, c8 = i & 7;
        *(float4*)((char*)Bh + row * 144 + c8 * 16) =
            *(const float4*)((const char*)g_Win_hi + row * 128 + c8 * 16);
        *(float4*)((char*)Bl + row * 144 + c8 * 16) =
            *(const float4*)((const char*)g_Win_lo + row * 128 + c8 * 16);
    }
    for (int i = t; i < 1024; i += 256) {            // A: 64 rows x 64 k
        int row = i >> 4, c4 = i & 15;
        int n = nbase + row;
        float4 v = make_float4(0.f, 0.f, 0.f, 0.f);
        if (n < N_NODES) v = *(const float4*)(X + (size_t)n * IN_DIMC + c4 * 4);
        union { __hip_bfloat16 e[4]; uint2 u; } ph, pl;
        split2(v.x, ph.e[0], pl.e[0]); split2(v.y, ph.e[1], pl.e[1]);
        split2(v.z, ph.e[2], pl.e[2]); split2(v.w, ph.e[3], pl.e[3]);
        *(uint2*)((char*)Ah + row * 144 + c4 * 8) = ph.u;
        *(uint2*)((char*)Al + row * 144 + c4 * 8) = pl.u;
    }
    __syncthreads();

    int lane = t & 63, w = t >> 6;
    int m16 = lane & 15, quad = lane >> 4;
    floatx4 acc[8];
#pragma unroll
    for (int i = 0; i < 8; ++i) acc[i] = floatx4{0.f, 0.f, 0.f, 0.f};

#pragma unroll
    for (int kk = 0; kk < 64; kk += 32) {
        bf16x8 ah = *(const bf16x8*)((const char*)Ah + (w * 16 + m16) * 144 + (kk + quad * 8) * 2);
        bf16x8 al = *(const bf16x8*)((const char*)Al + (w * 16 + m16) * 144 + (kk + quad * 8) * 2);
#pragma unroll
        for (int nt = 0; nt < 8; ++nt) {
            bf16x8 bh = *(const bf16x8*)((const char*)Bh + (nt * 16 + m16) * 144 + (kk + quad * 8) * 2);
            bf16x8 bl = *(const bf16x8*)((const char*)Bl + (nt * 16 + m16) * 144 + (kk + quad * 8) * 2);
            acc[nt] = __builtin_amdgcn_mfma_f32_16x16x32_bf16(ah, bh, acc[nt], 0, 0, 0);
            acc[nt] = __builtin_amdgcn_mfma_f32_16x16x32_bf16(al, bh, acc[nt], 0, 0, 0);
            acc[nt] = __builtin_amdgcn_mfma_f32_16x16x32_bf16(ah, bl, acc[nt], 0, 0, 0);
        }
    }
    float dotr[4] = {0.f, 0.f, 0.f, 0.f};
#pragma unroll
    for (int nt = 0; nt < 8; ++nt) {
        int ch = nt * 16 + m16;
        float bias = b[ch];
        float ak = att_k[ch];
#pragma unroll
        for (int r = 0; r < 4; ++r) {
            int n = nbase + w * 16 + quad * 4 + r;
            float o = acc[nt][r] + bias;
            if (n < N_NODES) h[(size_t)n * HIDC + ch] = o;
            dotr[r] += ak * o;
        }
    }
#pragma unroll
    for (int r = 0; r < 4; ++r) {
        float p = dotr[r];
        p += __shfl_xor(p, 1); p += __shfl_xor(p, 2);
        p += __shfl_xor(p, 4); p += __shfl_xor(p, 8);
        int n = nbase + w * 16 + quad * 4 + r;
        if (m16 == 0 && n < N_NODES) g_ekey[n] = __expf(p * INV_SQRT_H);
    }
}

// ---------------------------------------------------------------------------
// key_kernel: g_ekey[n] = exp(dot(bn_prev(h[n]), att_k)/sqrt(H)).
// Half-wave (32 lanes, float4/lane) per node; 2 nodes per wave.
// ---------------------------------------------------------------------------
__global__ __launch_bounds__(256) void key_kernel(const float* __restrict__ h,
                                                  const float* __restrict__ att_k,
                                                  int prev)
{
    int t = threadIdx.x;
    int lane = t & 63;
    int half = lane >> 5, sub = lane & 31;
    int n = (blockIdx.x * 4 + (t >> 6)) * 2 + half;
    if (n >= N_NODES) return;
    float4 x = ((const float4*)h)[(size_t)n * 32 + sub];
    float4 sc = ((const float4*)(g_bn_sc + prev * HIDC))[sub];
    float4 sh = ((const float4*)(g_bn_sh + prev * HIDC))[sub];
    float4 ak = ((const float4*)att_k)[sub];
    float p = (sc.x * x.x + sh.x) * ak.x + (sc.y * x.y + sh.y) * ak.y +
              (sc.z * x.z + sh.z) * ak.z + (sc.w * x.w + sh.w) * ak.w;
    p += __shfl_xor(p, 1);  p += __shfl_xor(p, 2);
    p += __shfl_xor(p, 4);  p += __shfl_xor(p, 8);
    p += __shfl_xor(p, 16);
    if (sub == 0) g_ekey[n] = __expf(p * INV_SQRT_H);
}

// ---------------------------------------------------------------------------
// layer_gemm: stage B (hi+lo) once; waves grid-stride over 16-node tiles,
// A fragments straight from global. Epilogue applies bn_prev to residual,
// accumulates BN stats in registers.
// ---------------------------------------------------------------------------
__global__ __launch_bounds__(256) void layer_gemm_kernel(
    float* __restrict__ h, const float* __restrict__ agg,
    const float* __restrict__ b, int layer, int prev)
{
    __shared__ __align__(16) __hip_bfloat16 Bh[128 * 136];
    __shared__ __align__(16) __hip_bfloat16 Bl[128 * 136];
    __shared__ float red[256];
    int t = threadIdx.x;
    const __hip_bfloat16* Wh = g_Wl_hi + layer * 16384;
    const __hip_bfloat16* Wlo = g_Wl_lo + layer * 16384;
    red[t] = 0.f;

    for (int i = t; i < 2048; i += 256) {      // B: [n=128][k=128], stride 272B
        int row = i >> 4, c8 = i & 15;
        *(float4*)((char*)Bh + row * 272 + c8 * 16) =
            *(const float4*)((const char*)Wh + row * 256 + c8 * 16);
        *(float4*)((char*)Bl + row * 272 + c8 * 16) =
            *(const float4*)((const char*)Wlo + row * 256 + c8 * 16);
    }
    __syncthreads();

    const int lane = t & 63, w = t >> 6;
    const int m16 = lane & 15, quad = lane >> 4;
    const int wid = blockIdx.x * 4 + w;
    const int nwaves = gridDim.x * 4;

    float bias[8], scp[8], shp[8];
#pragma unroll
    for (int nt = 0; nt < 8; ++nt) {
        int ch = nt * 16 + m16;
        bias[nt] = b[ch];
        scp[nt] = (prev >= 0) ? g_bn_sc[prev * HIDC + ch] : 1.f;
        shp[nt] = (prev >= 0) ? g_bn_sh[prev * HIDC + ch] : 0.f;
    }
    float sreg[8], qreg[8];
#pragma unroll
    for (int nt = 0; nt < 8; ++nt) { sreg[nt] = 0.f; qreg[nt] = 0.f; }

    for (int tile = wid; tile < NTILES; tile += nwaves) {
        const float* arow = agg + (size_t)(tile * 16 + m16) * HIDC + quad * 8;
        floatx4 acc[8];
#pragma unroll
        for (int i = 0; i < 8; ++i) acc[i] = floatx4{0.f, 0.f, 0.f, 0.f};

#pragma unroll
        for (int kk = 0; kk < 4; ++kk) {
            float4 a0 = *(const float4*)(arow + kk * 32);
            float4 a1 = *(const float4*)(arow + kk * 32 + 4);
            union { __hip_bfloat16 e[8]; bf16x8 v; } ah, al;
            split2(a0.x, ah.e[0], al.e[0]); split2(a0.y, ah.e[1], al.e[1]);
            split2(a0.z, ah.e[2], al.e[2]); split2(a0.w, ah.e[3], al.e[3]);
            split2(a1.x, ah.e[4], al.e[4]); split2(a1.y, ah.e[5], al.e[5]);
            split2(a1.z, ah.e[6], al.e[6]); split2(a1.w, ah.e[7], al.e[7]);
#pragma unroll
            for (int nt = 0; nt < 8; ++nt) {
                bf16x8 bh = *(const bf16x8*)((const char*)Bh + (nt * 16 + m16) * 272 + (kk * 32 + quad * 8) * 2);
                bf16x8 bl = *(const bf16x8*)((const char*)Bl + (nt * 16 + m16) * 272 + (kk * 32 + quad * 8) * 2);
                acc[nt] = __builtin_amdgcn_mfma_f32_16x16x32_bf16(ah.v, bh, acc[nt], 0, 0, 0);
                acc[nt] = __builtin_amdgcn_mfma_f32_16x16x32_bf16(al.v, bh, acc[nt], 0, 0, 0);
                acc[nt] = __builtin_amdgcn_mfma_f32_16x16x32_bf16(ah.v, bl, acc[nt], 0, 0, 0);
            }
        }
        int node0 = tile * 16 + quad * 4;
#pragma unroll
        for (int nt = 0; nt < 8; ++nt) {
            int ch = nt * 16 + m16;
#pragma unroll
            for (int r = 0; r < 4; ++r) {
                float* hp = h + (size_t)(node0 + r) * HIDC + ch;
                float o = scp[nt] * (*hp) + shp[nt] + acc[nt][r] + bias[nt];
                *hp = o;
                sreg[nt] += o;
                qreg[nt] += o * o;
            }
        }
    }

#pragma unroll
    for (int nt = 0; nt < 8; ++nt) {
        float s = sreg[nt], q = qreg[nt];
        s += __shfl_xor(s, 16); s += __shfl_xor(s, 32);
        q += __shfl_xor(q, 16); q += __shfl_xor(q, 32);
        if (quad == 0) {
            atomicAdd(&red[nt * 16 + m16], s);
            atomicAdd(&red[HIDC + nt * 16 + m16], q);
        }
    }
    __syncthreads();
    atomicAdd(&g_stats[layer * 2 * HIDC + t], red[t]);
}

// ---------------------------------------------------------------------------
// bn_prep: stats -> scale/shift (1 block, 128 threads)
// ---------------------------------------------------------------------------
__global__ void bn_prep_kernel(const float* __restrict__ gamma,
                               const float* __restrict__ beta, int layer)
{
    int c = threadIdx.x;
    if (c >= HIDC) return;
    const float invN = 1.0f / (float)N_NODES;
    float mean = g_stats[layer * 2 * HIDC + c] * invN;
    float var = g_stats[layer * 2 * HIDC + HIDC + c] * invN - mean * mean;
    float s = gamma[layer * HIDC + c] * rsqrtf(var + BN_EPS);
    g_bn_sc[layer * HIDC + c] = s;
    g_bn_sh[layer * HIDC + c] = beta[layer * HIDC + c] - mean * s;
}

// ---------------------------------------------------------------------------
// bn_apply (final output only): h = sc*h + sh
// ---------------------------------------------------------------------------
__global__ __launch_bounds__(256) void bn_apply_kernel(float* __restrict__ h, int layer)
{
    size_t idx = (size_t)blockIdx.x * 256 + threadIdx.x;  // float4 index
    if (idx >= (size_t)N_NODES * (HIDC / 4)) return;
    int cg = (int)(idx & 31);
    float4 sc = ((const float4*)(g_bn_sc + layer * HIDC))[cg];
    float4 sh = ((const float4*)(g_bn_sh + layer * HIDC))[cg];
    float4 v = ((float4*)h)[idx];
    v.x = sc.x * v.x + sh.x;
    v.y = sc.y * v.y + sh.y;
    v.z = sc.z * v.z + sh.z;
    v.w = sc.w * v.w + sh.w;
    ((float4*)h)[idx] = v;
}

// ---------------------------------------------------------------------------
extern "C" void kernel_launch(void* const* d_in, const int* in_sizes, int n_in,
                              void* d_out, int out_size, void* d_ws, size_t ws_size,
                              hipStream_t stream) {
    (void)in_sizes; (void)n_in; (void)out_size; (void)ws_size;
    const float* node_init = (const float*)d_in[0];
    const int*   eidx      = (const int*)d_in[1];   // [2,E] int32
    const float* elen      = (const float*)d_in[2];
    const float* W_in      = (const float*)d_in[3];
    const float* b_in      = (const float*)d_in[4];
    const float* att_k     = (const float*)d_in[5];
    const float* Wl        = (const float*)d_in[6]; // [2,128,128]
    const float* bl        = (const float*)d_in[7]; // [2,128]
    const float* gamma     = (const float*)d_in[8];
    const float* beta      = (const float*)d_in[9];

    float* h   = (float*)d_out;  // [N,128]
    float* agg = (float*)d_ws;   // [N,128] fp32

    const int* src = eidx;
    const int* dst = eidx + N_EDGES;

    zero_kernel<<<NB_SCAN, 256, 0, stream>>>();
    hist_kernel<<<(N_EDGES + 255) / 256, 256, 0, stream>>>(dst);
    scan1_kernel<<<NB_SCAN, 256, 0, stream>>>();
    scan2_kernel<<<1, 256, 0, stream>>>();
    scan3_kernel<<<NB_SCAN, 256, 0, stream>>>();
    scatter_kernel<<<(N_EDGES + 255) / 256, 256, 0, stream>>>(src, dst, elen);
    prep_w_kernel<<<(NLAYERS * 128 * 128 + 255) / 256, 256, 0, stream>>>(W_in, Wl);

    proj_mfma_kernel<<<(N_NODES + 63) / 64, 256, 0, stream>>>(node_init, b_in, att_k, h);

    for (int l = 0; l < NLAYERS; ++l) {
        if (l > 0)
            key_kernel<<<(N_NODES / 2 + 3) / 4, 256, 0, stream>>>(h, att_k, l - 1);
        edge_csr_kernel<<<(N_NODES + 3) / 4, 256, 0, stream>>>(h, agg, l - 1);
        layer_gemm_kernel<<<512, 256, 0, stream>>>(h, agg, bl + (size_t)l * HIDC, l, l - 1);
        bn_prep_kernel<<<1, 128, 0, stream>>>(gamma, beta, l);
    }
    bn_apply_kernel<<<(N_NODES * (HIDC / 4) + 255) / 256, 256, 0, stream>>>(h, NLAYERS - 1);
}